// Round 1
// baseline (3303.442 us; speedup 1.0000x reference)
//
#include <hip/hip_runtime.h>

typedef float v2f __attribute__((ext_vector_type(2)));

#define LOG2E 1.4426950408889634f
#define LN2   0.6931471805599453f

__device__ __forceinline__ float fexp2(float x) {
  float r; asm("v_exp_f32 %0, %1" : "=v"(r) : "v"(x)); return r;
}
__device__ __forceinline__ float frcp(float x) {
  float r; asm("v_rcp_f32 %0, %1" : "=v"(r) : "v"(x)); return r;
}
__device__ __forceinline__ float flog2(float x) {
  float r; asm("v_log_f32 %0, %1" : "=v"(r) : "v"(x)); return r;
}

// ---------------- embedding concat:  X[t][0..336) = [word(300) | pos(25) | 0pad] ----
__global__ void k_embed(const float* __restrict__ wv, const int* __restrict__ pidx,
                        const float* __restrict__ pemb, float* __restrict__ X) {
  int t = blockIdx.x;
  int pi = pidx[t];
  for (int c = threadIdx.x; c < 336; c += 128) {
    float v;
    if (c < 300)      v = wv[t * 300 + c];
    else if (c < 325) v = pemb[pi * 25 + (c - 300)];
    else              v = 0.f;
    X[t * 336 + c] = v;
  }
}

// ---------------- generic row repack with zero K-pad ------------------------------
__global__ void k_repack(const float* __restrict__ src, float* __restrict__ dst,
                         int sK, int dK) {
  int r = blockIdx.x;
  for (int c = threadIdx.x; c < dK; c += 128)
    dst[r * dK + c] = (c < sK) ? src[r * sK + c] : 0.f;
}

// ---------------- split fc1_W [100][500] -> Wab [200][256] (head rows, child rows) -
__global__ void k_wab(const float* __restrict__ fc1W, float* __restrict__ Wab) {
  int r = blockIdx.x;                       // 0..199
  int sr = (r < 100) ? r : r - 100;
  int so = (r < 100) ? 0 : 250;
  for (int c = threadIdx.x; c < 256; c += 128)
    Wab[r * 256 + c] = (c < 250) ? fc1W[sr * 500 + so + c] : 0.f;
}

// ---------------- biasAB (fc1_b for head rows, 0 for child) + sum(fc2_W) ----------
__global__ void k_misc(const float* __restrict__ fc1b, const float* __restrict__ fc2W,
                       float* __restrict__ biasAB, float* __restrict__ sumw) {
  __shared__ float red[128];
  int t = threadIdx.x;   // 128 threads
  for (int c = t; c < 256; c += 128)
    biasAB[c] = (c < 100) ? fc1b[c] : 0.f;
  float s = (t < 100) ? fc2W[t] : 0.f;
  red[t] = s; __syncthreads();
  for (int off = 64; off; off >>= 1) {
    if (t < off) red[t] += red[t + off];
    __syncthreads();
  }
  if (t == 0) sumw[0] = red[0];
}

// ---------------- tiled fp32 GEMM:  C[z][m][n] = sum_k A[m][k]*B[z][n][k] + bias[z][n]
// A:[M][K] row-major, B:[N][K] row-major (K mult of 16), 64x64 tile, 4x4 microtile.
#define BM 64
#define BN 64
#define BKK 16
__global__ __launch_bounds__(256) void k_gemm(
    const float* __restrict__ A, const float* __restrict__ Bw,
    const float* __restrict__ bias, float* __restrict__ C,
    int M, int N, int K, int ldC, long sBz, long sCz, long sbz) {
  const int z = blockIdx.z;
  const float* Bp = Bw + (size_t)z * sBz;
  const float* bp = bias + (size_t)z * sbz;
  float* Cp = C + (size_t)z * sCz;
  const int bm = blockIdx.y * BM, bn = blockIdx.x * BN;
  __shared__ __align__(16) float As[BKK][BM + 4];
  __shared__ __align__(16) float Bs[BKK][BN + 4];
  const int tid = threadIdx.x;
  const int tx = tid & 15, ty = tid >> 4;
  const int lr = tid >> 2;            // 0..63
  const int lk = (tid & 3) * 4;       // 0,4,8,12
  float acc[4][4];
#pragma unroll
  for (int a = 0; a < 4; ++a)
#pragma unroll
    for (int b = 0; b < 4; ++b) acc[a][b] = 0.f;

  int brow = bn + lr; if (brow >= N) brow = N - 1;   // clamp (pad cols unused)
  for (int k0 = 0; k0 < K; k0 += BKK) {
    float4 a4 = *(const float4*)(A + (size_t)(bm + lr) * K + k0 + lk);
    float4 b4 = *(const float4*)(Bp + (size_t)brow * K + k0 + lk);
    __syncthreads();
    As[lk + 0][lr] = a4.x; As[lk + 1][lr] = a4.y; As[lk + 2][lr] = a4.z; As[lk + 3][lr] = a4.w;
    Bs[lk + 0][lr] = b4.x; Bs[lk + 1][lr] = b4.y; Bs[lk + 2][lr] = b4.z; Bs[lk + 3][lr] = b4.w;
    __syncthreads();
#pragma unroll
    for (int kk = 0; kk < BKK; ++kk) {
      float4 av = *(const float4*)&As[kk][ty * 4];
      float4 bv = *(const float4*)&Bs[kk][tx * 4];
      float aa[4] = {av.x, av.y, av.z, av.w};
      float bb[4] = {bv.x, bv.y, bv.z, bv.w};
#pragma unroll
      for (int a = 0; a < 4; ++a)
#pragma unroll
        for (int b = 0; b < 4; ++b)
          acc[a][b] = __builtin_fmaf(aa[a], bb[b], acc[a][b]);
    }
  }
#pragma unroll
  for (int a = 0; a < 4; ++a) {
    int i = bm + ty * 4 + a;
#pragma unroll
    for (int b = 0; b < 4; ++b) {
      int j = bn + tx * 4 + b;
      if (j < N) Cp[(size_t)i * ldC + j] = acc[a][b] + bp[j];
    }
  }
}

// ---------------- LSTM recurrence, one block per direction -------------------------
// P: pre-gates [d][1024][500] (x@Wih^T + b), Whh: [d][500][125], hout: [1024][256]
// thread t owns gate rows t and t+256; weights live in VGPRs (v2f pairs).
__global__ __launch_bounds__(256, 1) void k_rec(const float* __restrict__ Pg,
                                                const float* __restrict__ Whh,
                                                float* __restrict__ hout) {
  const int d = blockIdx.x;
  const int t = threadIdx.x;
  const bool fwd = (d == 0);
  const float* P = Pg + (size_t)d * 1024 * 500;
  const float* W = Whh + (size_t)d * 500 * 125;
  const int g0 = t;
  const int g1 = t + 256;
  const bool v1 = (g1 < 500);

  v2f w0v[64], w1v[64];
  const float* w0p = W + (size_t)g0 * 125;
  const float* w1p = W + (size_t)g1 * 125;
#pragma unroll
  for (int j = 0; j < 64; ++j) {
    float a  = (2 * j     < 125) ? w0p[2 * j]     : 0.f;
    float b  = (2 * j + 1 < 125) ? w0p[2 * j + 1] : 0.f;
    v2f w; w.x = a; w.y = b; w0v[j] = w;
    float c2 = (v1 && 2 * j     < 125) ? w1p[2 * j]     : 0.f;
    float d2 = (v1 && 2 * j + 1 < 125) ? w1p[2 * j + 1] : 0.f;
    v2f u; u.x = c2; u.y = d2; w1v[j] = u;
  }

  __shared__ __align__(16) float hsh[128];   // h_{t-1}, zero-padded to 128
  __shared__ float gsh[512];                 // activated gates
  if (t < 128) hsh[t] = 0.f;
  float c = 0.f;
  __syncthreads();

  const int time0 = fwd ? 0 : 1023;
  float pre0 = P[(size_t)time0 * 500 + g0];
  float pre1 = v1 ? P[(size_t)time0 * 500 + g1] : 0.f;

  const bool isT0 = (t >= 250);     // gate id 250..255 -> g-gate (tanh)
  const bool isT1 = (g1 < 375);     // 256..374 -> g-gate (tanh), 375..499 -> o (sigm)

  for (int s = 0; s < 1024; ++s) {
    const int time = fwd ? s : 1023 - s;
    float cur0 = pre0, cur1 = pre1;
    if (s + 1 < 1024) {             // prefetch next step's pre-gates
      int tn = fwd ? (s + 1) : (1022 - s);
      pre0 = P[(size_t)tn * 500 + g0];
      pre1 = v1 ? P[(size_t)tn * 500 + g1] : 0.f;
    }
    v2f A0 = {0.f, 0.f}, A1 = {0.f, 0.f}, B0 = {0.f, 0.f}, B1 = {0.f, 0.f};
    const float4* h4 = (const float4*)hsh;
#pragma unroll
    for (int q = 0; q < 32; ++q) {
      float4 hh = h4[q];
      v2f ha; ha.x = hh.x; ha.y = hh.y;
      v2f hb; hb.x = hh.z; hb.y = hh.w;
      A0 = __builtin_elementwise_fma(w0v[2 * q],     ha, A0);
      A1 = __builtin_elementwise_fma(w0v[2 * q + 1], hb, A1);
      B0 = __builtin_elementwise_fma(w1v[2 * q],     ha, B0);
      B1 = __builtin_elementwise_fma(w1v[2 * q + 1], hb, B1);
    }
    float x0 = cur0 + (A0.x + A0.y) + (A1.x + A1.y);
    float x1 = cur1 + (B0.x + B0.y) + (B1.x + B1.y);
    // sigmoid(x) = rcp(1+exp(-x)); tanh(x) = 2*sigmoid(2x)-1
    float xx0 = isT0 ? 2.f * x0 : x0;
    float s0 = frcp(1.f + fexp2(-LOG2E * xx0));
    float a0 = isT0 ? 2.f * s0 - 1.f : s0;
    float xx1 = isT1 ? 2.f * x1 : x1;
    float s1 = frcp(1.f + fexp2(-LOG2E * xx1));
    float a1 = isT1 ? 2.f * s1 - 1.f : s1;
    gsh[g0] = a0;
    if (v1) gsh[g1] = a1;
    __syncthreads();
    if (t < 125) {
      float gi = gsh[t], gf = gsh[125 + t], gg = gsh[250 + t], go = gsh[375 + t];
      c = __builtin_fmaf(gf, c, gi * gg);
      float th = 2.f * frcp(1.f + fexp2(-2.f * LOG2E * c)) - 1.f;   // tanh(c)
      float h = go * th;
      hsh[t] = h;
      hout[(size_t)time * 256 + d * 125 + t] = h;
    }
    __syncthreads();
  }
}

// ---------------- pairwise scorer ---------------------------------------------------
// score(i,j) = sumW + fc2_b - sum_k (2*w_k)/(1+exp(2*(A[i][k]+B[j][k])))  (tanh identity)
__global__ __launch_bounds__(256) void k_pair(const float* __restrict__ AB,
    const float* __restrict__ fc2W, const float* __restrict__ fc2b,
    const float* __restrict__ sumw, float* __restrict__ outS,
    float* __restrict__ scoresT) {
  __shared__ float As[32][100];
  __shared__ float Bs[32][101];   // +1 pad: conflict-free Bs[tx][k]
  __shared__ float w2s[100];
  const int tid = threadIdx.x;
  const int i0 = blockIdx.y * 32, j0 = blockIdx.x * 32;
  for (int idx = tid; idx < 3200; idx += 256) {
    int r = idx / 100, k = idx - r * 100;
    As[r][k] = AB[(size_t)(i0 + r) * 200 + k];         // head contrib (fc1_b folded)
    Bs[r][k] = AB[(size_t)(j0 + r) * 200 + 100 + k];   // child contrib
  }
  if (tid < 100) w2s[tid] = 2.f * fc2W[tid];
  __syncthreads();
  const int tx = tid & 31, ty = tid >> 5;
  float acc[4] = {0.f, 0.f, 0.f, 0.f};
#pragma unroll 4
  for (int k = 0; k < 100; ++k) {
    float b = Bs[tx][k];
    float wk2 = w2s[k];
    float bs = b * (2.f * LOG2E);
#pragma unroll
    for (int q = 0; q < 4; ++q) {
      float a = As[ty + 8 * q][k];
      float r = frcp(1.f + fexp2(__builtin_fmaf(a, 2.f * LOG2E, bs)));
      acc[q] = __builtin_fmaf(wk2, r, acc[q]);
    }
  }
  float base = sumw[0] + fc2b[0];
  const int j = j0 + tx;
#pragma unroll
  for (int q = 0; q < 4; ++q) {
    int i = i0 + ty + 8 * q;
    float val = (i != j && j != 0) ? (base - acc[q]) : 0.f;
    outS[(size_t)i * 1024 + j] = val;
    scoresT[(size_t)j * 1024 + i] = val;
  }
}

// ---------------- per-child log-softmax contribution -------------------------------
__global__ __launch_bounds__(256) void k_soft(const float* __restrict__ scoresT,
    const int* __restrict__ parents, float* __restrict__ contrib) {
  const int j = blockIdx.x, tid = threadIdx.x;
  __shared__ float red[256];
  const float* row = scoresT + (size_t)j * 1024;
  float v0 = row[tid], v1 = row[tid + 256], v2 = row[tid + 512], v3 = row[tid + 768];
  float m = fmaxf(fmaxf(v0, v1), fmaxf(v2, v3));
  red[tid] = m; __syncthreads();
  for (int off = 128; off; off >>= 1) {
    if (tid < off) red[tid] = fmaxf(red[tid], red[tid + off]);
    __syncthreads();
  }
  m = red[0]; __syncthreads();
  float s = fexp2((v0 - m) * LOG2E) + fexp2((v1 - m) * LOG2E) +
            fexp2((v2 - m) * LOG2E) + fexp2((v3 - m) * LOG2E);
  red[tid] = s; __syncthreads();
  for (int off = 128; off; off >>= 1) {
    if (tid < off) red[tid] += red[tid + off];
    __syncthreads();
  }
  if (tid == 0) {
    float S = red[0];
    int p = parents[j];
    contrib[j] = row[p] - m - flog2(S) * LN2;
  }
}

__global__ __launch_bounds__(256) void k_loss(const float* __restrict__ contrib,
                                              float* __restrict__ out) {
  __shared__ float red[256];
  int tid = threadIdx.x;
  float s = contrib[tid] + contrib[tid + 256] + contrib[tid + 512] + contrib[tid + 768];
  red[tid] = s; __syncthreads();
  for (int off = 128; off; off >>= 1) {
    if (tid < off) red[tid] += red[tid + off];
    __syncthreads();
  }
  if (tid == 0) out[0] = -red[0] * (1.f / 1024.f);
}

// ---------------- launcher ---------------------------------------------------------
extern "C" void kernel_launch(void* const* d_in, const int* in_sizes, int n_in,
                              void* d_out, int out_size, void* d_ws, size_t ws_size,
                              hipStream_t stream) {
  const float* wv   = (const float*)d_in[0];
  const int*   pidx = (const int*)d_in[1];
  const int*   par  = (const int*)d_in[2];
  const float* pemb = (const float*)d_in[3];
  const float* Wih0 = (const float*)d_in[4];
  const float* Whh0 = (const float*)d_in[5];
  const float* b0   = (const float*)d_in[6];
  const float* Wih1 = (const float*)d_in[7];
  const float* Whh1 = (const float*)d_in[8];
  const float* b1   = (const float*)d_in[9];
  const float* fc1W = (const float*)d_in[10];
  const float* fc1b = (const float*)d_in[11];
  const float* fc2W = (const float*)d_in[12];
  const float* fc2b = (const float*)d_in[13];
  float* ws = (float*)d_ws;
  // workspace layout (float offsets)
  float* X      = ws + 0;        // 1024*336
  float* Wih0p  = ws + 344064;   // 2*500*336
  float* P0     = ws + 680064;   // 2*1024*500
  float* h0     = ws + 1704064;  // 1024*256
  float* Wih1p  = ws + 1966208;  // 2*500*256
  float* P1     = ws + 2222208;  // 2*1024*500
  float* h1     = ws + 3246208;  // 1024*256
  float* Wab    = ws + 3508352;  // 200*256
  float* biasAB = ws + 3559552;  // 256
  float* AB     = ws + 3559808;  // 1024*200
  float* scT    = ws + 3764608;  // 1024*1024
  float* contrib= ws + 4813184;  // 1024
  float* sumw   = ws + 4814208;  // 1
  float* out = (float*)d_out;

  // zero the padded h buffers (cols 250..255 must be 0 for the K=256 GEMMs)
  hipMemsetAsync(h0, 0, 1024 * 256 * sizeof(float), stream);
  hipMemsetAsync(h1, 0, 1024 * 256 * sizeof(float), stream);

  k_embed <<<1024, 128, 0, stream>>>(wv, pidx, pemb, X);
  k_repack<<<1000, 128, 0, stream>>>(Wih0, Wih0p, 325, 336);
  k_repack<<<1000, 128, 0, stream>>>(Wih1, Wih1p, 250, 256);
  k_wab   <<<200, 128, 0, stream>>>(fc1W, Wab);
  k_misc  <<<1, 128, 0, stream>>>(fc1b, fc2W, biasAB, sumw);

  // layer 0
  k_gemm<<<dim3(8, 16, 2), 256, 0, stream>>>(X, Wih0p, b0, P0, 1024, 500, 336, 500,
                                             500L * 336, 1024L * 500, 500L);
  k_rec <<<2, 256, 0, stream>>>(P0, Whh0, h0);
  // layer 1
  k_gemm<<<dim3(8, 16, 2), 256, 0, stream>>>(h0, Wih1p, b1, P1, 1024, 500, 256, 500,
                                             500L * 256, 1024L * 500, 500L);
  k_rec <<<2, 256, 0, stream>>>(P1, Whh1, h1);
  // head/child projections (fc1_b folded into head half via biasAB)
  k_gemm<<<dim3(4, 16, 1), 256, 0, stream>>>(h1, Wab, biasAB, AB, 1024, 200, 256, 200,
                                             0L, 0L, 0L);
  // pairwise scores + transposed copy
  k_pair<<<dim3(32, 32), 256, 0, stream>>>(AB, fc2W, fc2b, sumw, out + 1, scT);
  // per-child log-softmax and loss
  k_soft<<<1024, 256, 0, stream>>>(scT, par, contrib);
  k_loss<<<1, 256, 0, stream>>>(contrib, out);
}

// Round 2
// 1350.380 us; speedup vs baseline: 2.4463x; 2.4463x over previous
//
#include <hip/hip_runtime.h>

typedef float v2f __attribute__((ext_vector_type(2)));

#define LOG2E 1.4426950408889634f
#define LN2   0.6931471805599453f

__device__ __forceinline__ float fexp2(float x) {
  float r; asm("v_exp_f32 %0, %1" : "=v"(r) : "v"(x)); return r;
}
__device__ __forceinline__ float frcp(float x) {
  float r; asm("v_rcp_f32 %0, %1" : "=v"(r) : "v"(x)); return r;
}
__device__ __forceinline__ float flog2(float x) {
  float r; asm("v_log_f32 %0, %1" : "=v"(r) : "v"(x)); return r;
}
// quad_perm lane swaps on the VALU pipe (no LDS traffic)
__device__ __forceinline__ float dpp_xor1(float v) {
  return __builtin_bit_cast(float,
      __builtin_amdgcn_update_dpp(0, __builtin_bit_cast(int, v), 0xB1, 0xF, 0xF, true));
}
__device__ __forceinline__ float dpp_xor2(float v) {
  return __builtin_bit_cast(float,
      __builtin_amdgcn_update_dpp(0, __builtin_bit_cast(int, v), 0x4E, 0xF, 0xF, true));
}

// ---------------- embedding concat:  X[t][0..336) = [word(300) | pos(25) | 0pad] ----
__global__ void k_embed(const float* __restrict__ wv, const int* __restrict__ pidx,
                        const float* __restrict__ pemb, float* __restrict__ X) {
  int t = blockIdx.x;
  int pi = pidx[t];
  for (int c = threadIdx.x; c < 336; c += 128) {
    float v;
    if (c < 300)      v = wv[t * 300 + c];
    else if (c < 325) v = pemb[pi * 25 + (c - 300)];
    else              v = 0.f;
    X[t * 336 + c] = v;
  }
}

// ---------------- generic row repack with zero K-pad ------------------------------
__global__ void k_repack(const float* __restrict__ src, float* __restrict__ dst,
                         int sK, int dK) {
  int r = blockIdx.x;
  for (int c = threadIdx.x; c < dK; c += 128)
    dst[r * dK + c] = (c < sK) ? src[r * sK + c] : 0.f;
}

// ---------------- split fc1_W [100][500] -> Wab [200][256] ------------------------
__global__ void k_wab(const float* __restrict__ fc1W, float* __restrict__ Wab) {
  int r = blockIdx.x;                       // 0..199
  int sr = (r < 100) ? r : r - 100;
  int so = (r < 100) ? 0 : 250;
  for (int c = threadIdx.x; c < 256; c += 128)
    Wab[r * 256 + c] = (c < 250) ? fc1W[sr * 500 + so + c] : 0.f;
}

// ---------------- biasAB + sum(fc2_W) ----------------------------------------------
__global__ void k_misc(const float* __restrict__ fc1b, const float* __restrict__ fc2W,
                       float* __restrict__ biasAB, float* __restrict__ sumw) {
  __shared__ float red[128];
  int t = threadIdx.x;   // 128 threads
  for (int c = t; c < 256; c += 128)
    biasAB[c] = (c < 100) ? fc1b[c] : 0.f;
  float s = (t < 100) ? fc2W[t] : 0.f;
  red[t] = s; __syncthreads();
  for (int off = 64; off; off >>= 1) {
    if (t < off) red[t] += red[t + off];
    __syncthreads();
  }
  if (t == 0) sumw[0] = red[0];
}

// ---------------- tiled fp32 GEMM:  C = A @ B^T + bias -----------------------------
// A:[M][K], B:[N][K] (K mult of 16). transOut=0: C[m][n] (ldC=row len).
// transOut=1: C[n][m] (ldC = M), LDS-staged transpose for coalesced stores.
#define BM 64
#define BN 64
#define BKK 16
__global__ __launch_bounds__(256) void k_gemm(
    const float* __restrict__ A, const float* __restrict__ Bw,
    const float* __restrict__ bias, float* __restrict__ C,
    int M, int N, int K, int ldC, long sBz, long sCz, long sbz, int transOut) {
  const int z = blockIdx.z;
  const float* Bp = Bw + (size_t)z * sBz;
  const float* bp = bias + (size_t)z * sbz;
  float* Cp = C + (size_t)z * sCz;
  const int bm = blockIdx.y * BM, bn = blockIdx.x * BN;
  __shared__ __align__(16) float As[BKK][BM + 4];
  __shared__ __align__(16) float Bs[BKK][BN + 4];
  __shared__ float Ts[BN][BM + 1];
  const int tid = threadIdx.x;
  const int tx = tid & 15, ty = tid >> 4;
  const int lr = tid >> 2;            // 0..63
  const int lk = (tid & 3) * 4;       // 0,4,8,12
  float acc[4][4];
#pragma unroll
  for (int a = 0; a < 4; ++a)
#pragma unroll
    for (int b = 0; b < 4; ++b) acc[a][b] = 0.f;

  int brow = bn + lr; if (brow >= N) brow = N - 1;   // clamp (pad cols unused)
  for (int k0 = 0; k0 < K; k0 += BKK) {
    float4 a4 = *(const float4*)(A + (size_t)(bm + lr) * K + k0 + lk);
    float4 b4 = *(const float4*)(Bp + (size_t)brow * K + k0 + lk);
    __syncthreads();
    As[lk + 0][lr] = a4.x; As[lk + 1][lr] = a4.y; As[lk + 2][lr] = a4.z; As[lk + 3][lr] = a4.w;
    Bs[lk + 0][lr] = b4.x; Bs[lk + 1][lr] = b4.y; Bs[lk + 2][lr] = b4.z; Bs[lk + 3][lr] = b4.w;
    __syncthreads();
#pragma unroll
    for (int kk = 0; kk < BKK; ++kk) {
      float4 av = *(const float4*)&As[kk][ty * 4];
      float4 bv = *(const float4*)&Bs[kk][tx * 4];
      float aa[4] = {av.x, av.y, av.z, av.w};
      float bb[4] = {bv.x, bv.y, bv.z, bv.w};
#pragma unroll
      for (int a = 0; a < 4; ++a)
#pragma unroll
        for (int b = 0; b < 4; ++b)
          acc[a][b] = __builtin_fmaf(aa[a], bb[b], acc[a][b]);
    }
  }
  if (!transOut) {
#pragma unroll
    for (int a = 0; a < 4; ++a) {
      int i = bm + ty * 4 + a;
#pragma unroll
      for (int b = 0; b < 4; ++b) {
        int j = bn + tx * 4 + b;
        if (j < N) Cp[(size_t)i * ldC + j] = acc[a][b] + bp[j];
      }
    }
  } else {
    __syncthreads();
#pragma unroll
    for (int a = 0; a < 4; ++a)
#pragma unroll
      for (int b = 0; b < 4; ++b) {
        int jn = bn + tx * 4 + b; if (jn >= N) jn = N - 1;
        Ts[tx * 4 + b][ty * 4 + a] = acc[a][b] + bp[jn];
      }
    __syncthreads();
    const int n2 = tid >> 2, mq = (tid & 3) * 16;
    const int n = bn + n2;
    if (n < N) {
#pragma unroll
      for (int r = 0; r < 4; ++r) {
        int m0 = mq + r * 4;
        float4 v;
        v.x = Ts[n2][m0 + 0]; v.y = Ts[n2][m0 + 1];
        v.z = Ts[n2][m0 + 2]; v.w = Ts[n2][m0 + 3];
        *(float4*)(Cp + (size_t)n * ldC + bm + m0) = v;
      }
    }
  }
}

// ---------------- LSTM recurrence v2 ----------------------------------------------
// Pt: transposed pre-gates [d][500][1024] (row r = gate-row, col = time).
// Whh: [d][500][125]. hout: [1024][256] (d*125+u).
// 512 threads: t = 4*u + sub; thread owns rows {g*125+u} for g=0..3, cols sub*32..+31.
// Weights in VGPRs (128), h double-buffered in LDS, DPP quad reductions, 1 barrier/step,
// hout staged in LDS history flushed every 32 steps, P prefetched 8 steps/chunk in regs.
__global__ __launch_bounds__(512, 2) void k_rec(const float* __restrict__ Pt,
                                                const float* __restrict__ Whh,
                                                float* __restrict__ hout) {
  const int d = blockIdx.x;
  const bool fwd = (d == 0);
  const int t = threadIdx.x;
  int u = t >> 2; const bool active = (u < 125); if (u > 124) u = 124;
  const int sub = t & 3;

  // ---- weights into VGPRs: 4 gates x 16 v2f (cols sub*32 + 2j) ----
  const float* Wd = Whh + (size_t)d * 500 * 125;
  v2f w[4][16];
#pragma unroll
  for (int g = 0; g < 4; ++g) {
    const float* wr = Wd + (size_t)(g * 125 + u) * 125;
#pragma unroll
    for (int j = 0; j < 16; ++j) {
      int col = sub * 32 + 2 * j;
      v2f ww;
      ww.x = (col     < 125) ? wr[col]     : 0.f;
      ww.y = (col + 1 < 125) ? wr[col + 1] : 0.f;
      w[g][j] = ww;
    }
  }

  // ---- LDS ----
  __shared__ __align__(16) float hb[2][160];   // padded h: addr(c)=c+4*(c>>5), 144 used
  __shared__ float hist[32][128];              // h history (32 steps) for batched hout
  for (int i = t; i < 320; i += 512) ((float*)hb)[i] = 0.f;

  // ---- per-thread P^T column ----
  const int prow = sub * 125 + u;              // gate = sub
  const float4* Pr = (const float4*)(Pt + (size_t)d * 500 * 1024 + (size_t)prow * 1024);

  // activation constants: sub==2 is the g-gate (tanh); others sigmoid
  const float sM = (sub == 2) ? 2.f : 1.f;
  const float sA = (sub == 2) ? 2.f : 1.f;
  const float sB = (sub == 2) ? -1.f : 0.f;
  const bool m0s = (sub == 0), m1s = (sub == 1), m2s = (sub == 2);

  float cst = 0.f;
  // chunk 0 pre-gates
  float4 cura = Pr[fwd ? 0 : 254];
  float4 curb = Pr[fwd ? 1 : 255];
  __syncthreads();

  for (int cb = 0; cb < 128; ++cb) {
    // prefetch next chunk (drains at the next barrier; once per 8 steps)
    int nc = (cb + 1 < 128) ? cb + 1 : cb;
    float4 nxta = Pr[fwd ? 2 * nc     : 254 - 2 * nc];
    float4 nxtb = Pr[fwd ? 2 * nc + 1 : 255 - 2 * nc];
#pragma unroll
    for (int e = 0; e < 8; ++e) {
      const int buf = e & 1;
      // pre-gate for this step (element select folds at compile time)
      float pf = (e == 0) ? cura.x : (e == 1) ? cura.y : (e == 2) ? cura.z : (e == 3) ? cura.w
               : (e == 4) ? curb.x : (e == 5) ? curb.y : (e == 6) ? curb.z : curb.w;
      float pb = (e == 0) ? curb.w : (e == 1) ? curb.z : (e == 2) ? curb.y : (e == 3) ? curb.x
               : (e == 4) ? cura.w : (e == 5) ? cura.z : (e == 6) ? cura.y : cura.x;
      float pre = fwd ? pf : pb;
      // ---- matvec: 4 gate-rows x 32 cols against h chunk `sub` ----
      const float4* hp = (const float4*)&hb[buf][36 * sub];
      v2f a0 = {0.f, 0.f}, a1 = {0.f, 0.f}, a2 = {0.f, 0.f}, a3 = {0.f, 0.f};
#pragma unroll
      for (int q = 0; q < 8; ++q) {
        float4 hv = hp[q];
        v2f ha; ha.x = hv.x; ha.y = hv.y;
        v2f hc; hc.x = hv.z; hc.y = hv.w;
        a0 = __builtin_elementwise_fma(w[0][2 * q], ha, a0);
        a0 = __builtin_elementwise_fma(w[0][2 * q + 1], hc, a0);
        a1 = __builtin_elementwise_fma(w[1][2 * q], ha, a1);
        a1 = __builtin_elementwise_fma(w[1][2 * q + 1], hc, a1);
        a2 = __builtin_elementwise_fma(w[2][2 * q], ha, a2);
        a2 = __builtin_elementwise_fma(w[2][2 * q + 1], hc, a2);
        a3 = __builtin_elementwise_fma(w[3][2 * q], ha, a3);
        a3 = __builtin_elementwise_fma(w[3][2 * q + 1], hc, a3);
      }
      float p0 = a0.x + a0.y, p1 = a1.x + a1.y, p2 = a2.x + a2.y, p3 = a3.x + a3.y;
      // ---- reduce over the 4 sub-lanes (DPP quad butterflies) ----
      p0 += dpp_xor1(p0); p0 += dpp_xor2(p0);
      p1 += dpp_xor1(p1); p1 += dpp_xor2(p1);
      p2 += dpp_xor1(p2); p2 += dpp_xor2(p2);
      p3 += dpp_xor1(p3); p3 += dpp_xor2(p3);
      // each lane keeps its own gate (g == sub), adds pre-gate, activates
      float x = m0s ? p0 : m1s ? p1 : m2s ? p2 : p3;
      x += pre;
      float sg = frcp(1.f + fexp2(-LOG2E * (sM * x)));
      float a = __builtin_fmaf(sA, sg, sB);
      // ---- gather i,f,g,o into sub0 lane ----
      float fg = dpp_xor1(a);     // sub0: f
      float gg = dpp_xor2(a);     // sub0: g
      float og = dpp_xor2(fg);    // sub0: o
      cst = __builtin_fmaf(fg, cst, a * gg);
      float th = __builtin_fmaf(2.f, frcp(1.f + fexp2(-2.f * LOG2E * cst)), -1.f);
      float h = og * th;
      if (m0s && active) {
        hb[buf ^ 1][u + 4 * (u >> 5)] = h;
        hist[(cb & 3) * 8 + e][u] = h;
      }
      __syncthreads();
    }
    if ((cb & 3) == 3) {   // flush 32 steps of h to global
      const int S0 = (cb - 3) * 8;
#pragma unroll
      for (int k = 0; k < 8; ++k) {
        int idx = t + k * 512;
        int r = idx >> 7, u2 = idx & 127;
        if (u2 < 125) {
          int step = S0 + r;
          int time = fwd ? step : 1023 - step;
          hout[(size_t)time * 256 + d * 125 + u2] = hist[r][u2];
        }
      }
      __syncthreads();
    }
    cura = nxta; curb = nxtb;
  }
}

// ---------------- pairwise scorer ---------------------------------------------------
__global__ __launch_bounds__(256) void k_pair(const float* __restrict__ AB,
    const float* __restrict__ fc2W, const float* __restrict__ fc2b,
    const float* __restrict__ sumw, float* __restrict__ outS,
    float* __restrict__ scoresT) {
  __shared__ float As[32][100];
  __shared__ float Bs[32][101];
  __shared__ float w2s[100];
  const int tid = threadIdx.x;
  const int i0 = blockIdx.y * 32, j0 = blockIdx.x * 32;
  for (int idx = tid; idx < 3200; idx += 256) {
    int r = idx / 100, k = idx - r * 100;
    As[r][k] = AB[(size_t)(i0 + r) * 200 + k];
    Bs[r][k] = AB[(size_t)(j0 + r) * 200 + 100 + k];
  }
  if (tid < 100) w2s[tid] = 2.f * fc2W[tid];
  __syncthreads();
  const int tx = tid & 31, ty = tid >> 5;
  float acc[4] = {0.f, 0.f, 0.f, 0.f};
#pragma unroll 4
  for (int k = 0; k < 100; ++k) {
    float b = Bs[tx][k];
    float wk2 = w2s[k];
    float bs = b * (2.f * LOG2E);
#pragma unroll
    for (int q = 0; q < 4; ++q) {
      float a = As[ty + 8 * q][k];
      float r = frcp(1.f + fexp2(__builtin_fmaf(a, 2.f * LOG2E, bs)));
      acc[q] = __builtin_fmaf(wk2, r, acc[q]);
    }
  }
  float base = sumw[0] + fc2b[0];
  const int j = j0 + tx;
#pragma unroll
  for (int q = 0; q < 4; ++q) {
    int i = i0 + ty + 8 * q;
    float val = (i != j && j != 0) ? (base - acc[q]) : 0.f;
    outS[(size_t)i * 1024 + j] = val;
    scoresT[(size_t)j * 1024 + i] = val;
  }
}

// ---------------- per-child log-softmax contribution -------------------------------
__global__ __launch_bounds__(256) void k_soft(const float* __restrict__ scoresT,
    const int* __restrict__ parents, float* __restrict__ contrib) {
  const int j = blockIdx.x, tid = threadIdx.x;
  __shared__ float red[256];
  const float* row = scoresT + (size_t)j * 1024;
  float v0 = row[tid], v1 = row[tid + 256], v2 = row[tid + 512], v3 = row[tid + 768];
  float m = fmaxf(fmaxf(v0, v1), fmaxf(v2, v3));
  red[tid] = m; __syncthreads();
  for (int off = 128; off; off >>= 1) {
    if (tid < off) red[tid] = fmaxf(red[tid], red[tid + off]);
    __syncthreads();
  }
  m = red[0]; __syncthreads();
  float s = fexp2((v0 - m) * LOG2E) + fexp2((v1 - m) * LOG2E) +
            fexp2((v2 - m) * LOG2E) + fexp2((v3 - m) * LOG2E);
  red[tid] = s; __syncthreads();
  for (int off = 128; off; off >>= 1) {
    if (tid < off) red[tid] += red[tid + off];
    __syncthreads();
  }
  if (tid == 0) {
    float S = red[0];
    int p = parents[j];
    contrib[j] = row[p] - m - flog2(S) * LN2;
  }
}

__global__ __launch_bounds__(256) void k_loss(const float* __restrict__ contrib,
                                              float* __restrict__ out) {
  __shared__ float red[256];
  int tid = threadIdx.x;
  float s = contrib[tid] + contrib[tid + 256] + contrib[tid + 512] + contrib[tid + 768];
  red[tid] = s; __syncthreads();
  for (int off = 128; off; off >>= 1) {
    if (tid < off) red[tid] += red[tid + off];
    __syncthreads();
  }
  if (tid == 0) out[0] = -red[0] * (1.f / 1024.f);
}

// ---------------- launcher ---------------------------------------------------------
extern "C" void kernel_launch(void* const* d_in, const int* in_sizes, int n_in,
                              void* d_out, int out_size, void* d_ws, size_t ws_size,
                              hipStream_t stream) {
  const float* wv   = (const float*)d_in[0];
  const int*   pidx = (const int*)d_in[1];
  const int*   par  = (const int*)d_in[2];
  const float* pemb = (const float*)d_in[3];
  const float* Wih0 = (const float*)d_in[4];
  const float* Whh0 = (const float*)d_in[5];
  const float* b0   = (const float*)d_in[6];
  const float* Wih1 = (const float*)d_in[7];
  const float* Whh1 = (const float*)d_in[8];
  const float* b1   = (const float*)d_in[9];
  const float* fc1W = (const float*)d_in[10];
  const float* fc1b = (const float*)d_in[11];
  const float* fc2W = (const float*)d_in[12];
  const float* fc2b = (const float*)d_in[13];
  float* ws = (float*)d_ws;
  // workspace layout (float offsets)
  float* X      = ws + 0;        // 1024*336
  float* Wih0p  = ws + 344064;   // 2*500*336
  float* Pt0    = ws + 680064;   // 2*500*1024 (transposed pre-gates, layer 0)
  float* h0     = ws + 1704064;  // 1024*256
  float* Wih1p  = ws + 1966208;  // 2*500*256
  float* Pt1    = ws + 2222208;  // 2*500*1024 (transposed pre-gates, layer 1)
  float* h1     = ws + 3246208;  // 1024*256
  float* Wab    = ws + 3508352;  // 200*256
  float* biasAB = ws + 3559552;  // 256
  float* AB     = ws + 3559808;  // 1024*200
  float* scT    = ws + 3764608;  // 1024*1024
  float* contrib= ws + 4813184;  // 1024
  float* sumw   = ws + 4814208;  // 1
  float* out = (float*)d_out;

  // zero padded h buffers (cols 250..255 must stay 0 for the K=256 GEMMs)
  hipMemsetAsync(h0, 0, 1024 * 256 * sizeof(float), stream);
  hipMemsetAsync(h1, 0, 1024 * 256 * sizeof(float), stream);

  k_embed <<<1024, 128, 0, stream>>>(wv, pidx, pemb, X);
  k_repack<<<1000, 128, 0, stream>>>(Wih0, Wih0p, 325, 336);
  k_repack<<<1000, 128, 0, stream>>>(Wih1, Wih1p, 250, 256);
  k_wab   <<<200, 128, 0, stream>>>(fc1W, Wab);
  k_misc  <<<1, 128, 0, stream>>>(fc1b, fc2W, biasAB, sumw);

  // layer 0 (pre-gates stored transposed: Pt[z][n][m], ldC = 1024)
  k_gemm<<<dim3(8, 16, 2), 256, 0, stream>>>(X, Wih0p, b0, Pt0, 1024, 500, 336, 1024,
                                             500L * 336, 500L * 1024, 500L, 1);
  k_rec <<<2, 512, 0, stream>>>(Pt0, Whh0, h0);
  // layer 1
  k_gemm<<<dim3(8, 16, 2), 256, 0, stream>>>(h0, Wih1p, b1, Pt1, 1024, 500, 256, 1024,
                                             500L * 256, 500L * 1024, 500L, 1);
  k_rec <<<2, 512, 0, stream>>>(Pt1, Whh1, h1);
  // head/child projections (fc1_b folded into head half via biasAB)
  k_gemm<<<dim3(4, 16, 1), 256, 0, stream>>>(h1, Wab, biasAB, AB, 1024, 200, 256, 200,
                                             0L, 0L, 0L, 0);
  // pairwise scores + transposed copy
  k_pair<<<dim3(32, 32), 256, 0, stream>>>(AB, fc2W, fc2b, sumw, out + 1, scT);
  // per-child log-softmax and loss
  k_soft<<<1024, 256, 0, stream>>>(scT, par, contrib);
  k_loss<<<1, 256, 0, stream>>>(contrib, out);
}